// Round 4
// baseline (460.047 us; speedup 1.0000x reference)
//
#include <hip/hip_runtime.h>

#define HH 512
#define WW 512
// sigmoid(10*t) = 1/(1 + 2^(-K*t));  K = 10*log2(e)
#define KSL 14.426950408889634f
#define FOURK 57.707801635558536f   // 4*KSL

typedef float f2 __attribute__((ext_vector_type(2)));

// sigmoid(10*t) where arg == -K*t : one v_exp_f32 + one v_rcp_f32
__device__ __forceinline__ float sig_arg(float arg) {
    float e = __builtin_amdgcn_exp2f(arg);
    return __builtin_amdgcn_rcpf(1.0f + e);
}
// Q = 2^(K*|x|)
__device__ __forceinline__ float QE(float x) {
    return __builtin_amdgcn_exp2f(KSL * fabsf(x));
}
// one inner-sum term: sigm(ad - X) = rcp(1 + Q_X * P_ad)
__device__ __forceinline__ float term(float qx, float p) {
    return __builtin_amdgcn_rcpf(fmaf(qx, p, 1.0f));
}

// One block = one full output row (512 px) of one (b, c):
//   256 threads x 2 px. Per plane the block writes ONE contiguous 2KB row
//   (vs 1KB chunks @ 2KB stride before). Row index is XCD-slab swizzled so
//   each XCD owns a contiguous 64-row slab per plane -> dense L2 evictions.
// 2 px/thread shrinks live state (~100 VGPR) -> 4 waves/SIMD vs 3.
__global__ __launch_bounds__(256, 4) void edge_kernel(const float* __restrict__ x,
                                                      float* __restrict__ out) {
    const int t  = threadIdx.x;
    const int w0 = t * 2;                         // float2-aligned pixel pair
    const int hs = blockIdx.x;                    // 512 rows, x-fastest dispatch
    const int h  = ((hs & 7) << 6) | (hs >> 3);   // XCD slab swizzle (bijective)
    const int z  = blockIdx.y;                    // z = b*3 + c
    const int b  = z / 3;
    const int c  = z - 3 * b;

    float* outp = out + (((size_t)(b * 24 + c * 8) * HH + h) * WW + w0);
    const int PL = HH * WW;                       // plane stride in floats

    if (h < 2 || h >= HH - 2) {                   // h-exterior rows: all zero
        const f2 zf = {0.f, 0.f};
        #pragma unroll
        for (int k = 0; k < 8; ++k)
            __builtin_nontemporal_store(zf, (f2*)(outp + k * PL));
        return;
    }

    const int cm = (c + 2) % 3, cp = (c + 1) % 3;
    const int wl = (w0 == 0) ? 0 : (w0 - 1);
    const int wr = (w0 + 2 >= WW) ? (WW - 1) : (w0 + 2);

    // window col i <-> image col w0-1+i (0=left halo, 1..2=pair, 3=right halo)
    float S[4][4], M[3][4], P[3][4];
    {
        const float* rp = x + (((size_t)(b * 3 + c) * HH + (h - 2)) * WW);
        #pragma unroll
        for (int r = 0; r < 4; ++r) {
            const float* row = rp + r * WW;
            const f2 m = *(const f2*)(row + w0);
            S[r][1] = m.x; S[r][2] = m.y;
            if (r > 0) { S[r][0] = row[wl]; S[r][3] = row[wr]; }
        }
    }
    {
        const float* rp = x + (((size_t)(b * 3 + cm) * HH + (h - 2)) * WW);
        #pragma unroll
        for (int r = 0; r < 3; ++r) {
            const float* row = rp + r * WW;
            const f2 m = *(const f2*)(row + w0);
            M[r][1] = m.x; M[r][2] = m.y;
            if (r != 1) { M[r][0] = row[wl]; M[r][3] = row[wr]; }
        }
    }
    {
        const float* rp = x + (((size_t)(b * 3 + cp) * HH + (h - 2)) * WW);
        #pragma unroll
        for (int r = 0; r < 3; ++r) {
            const float* row = rp + r * WW;
            const f2 m = *(const f2*)(row + w0);
            P[r][1] = m.x; P[r][2] = m.y;
            if (r != 1) { P[r][0] = row[wl]; }    // right halo never used
        }
    }

    float acc[8][2];
    #pragma unroll
    for (int q = 0; q < 2; ++q) {
        const float v = S[2][q + 1], u = S[1][q + 1];
        const float d10   = u           - v;
        const float dn10  = S[3][q + 1] - v;
        const float d01   = S[2][q]     - v;
        const float dn01  = S[2][q + 2] - v;
        const float d11   = S[1][q]     - v;
        const float dnn11 = S[3][q + 2] - v;
        const float dn11  = S[3][q]     - v;
        const float d1n1  = S[1][q + 2] - v;
        const float r_d10 = S[0][q + 1] - u;
        const float r_d01 = S[1][q]     - u;

        const float A01m   = M[2][q]     - M[2][q + 1];
        const float An01m  = M[2][q + 2] - M[2][q + 1];
        const float rA11m  = M[0][q]     - M[1][q + 1];
        const float rAn11m = M[2][q]     - M[1][q + 1];
        const float rA1n1m = M[0][q + 2] - M[1][q + 1];
        const float rA11p  = P[0][q]     - P[1][q + 1];
        const float rAn11p = P[2][q]     - P[1][q + 1];

        // shared Q factors: 2^(K*|diff|), one exp each (17 total)
        const float q10    = QE(d10),    qn10   = QE(dn10);
        const float q01    = QE(d01),    qn01   = QE(dn01);
        const float q11    = QE(d11),    qdn11  = QE(dn11);
        const float q1n1   = QE(d1n1),   qnn11  = QE(dnn11);
        const float qr10   = QE(r_d10),  qr01   = QE(r_d01);
        const float qA01m  = QE(A01m),   qAn01m = QE(An01m);
        const float qA11m  = QE(rA11m),  qAn11m = QE(rAn11m);
        const float qA1n1m = QE(rA1n1m);
        const float qA11p  = QE(rA11p),  qAn11p = QE(rAn11p);

        const float msk = ((w0 + q) >= 2 && (w0 + q) < WW - 2) ? 1.0f : 0.0f;

        // ---- branch 10 ----
        const float a10  = fabsf(d10);
        const float r10  = __builtin_amdgcn_rcpf(1.0f + q10);  // sigm(-a10)
        const float om10 = 1.0f - r10;                          // sigm(a10)
        const float ad10 = a10 * om10;
        const float P10  = __builtin_amdgcn_exp2f(-KSL * ad10);
        const float e10s = term(q01, P10) + term(qn01, P10) + term(qn10, P10)
                         + 2.0f * term(qA01m, P10)             // repeated in ref
                         + term(qAn01m, P10);
        const float g10 = msk * sig_arg(fmaf(e10s, -KSL, FOURK));
        const float s10 = (d10 >= 0.0f) ? om10 : r10;           // sigm(d10)
        acc[0][q] = g10 * s10;
        acc[1][q] = fmaf(-s10, g10, g10);                       // g*(1-s)

        // ---- branch 01 ---- (ref scales ad_01 by sigm(ad_10))
        const float sad10 = __builtin_amdgcn_rcpf(1.0f + P10);  // sigm(ad10)
        const float ad01  = fabsf(d01) * sad10;
        const float P01   = __builtin_amdgcn_exp2f(-KSL * ad01);
        const float e01s = 2.0f * term(q10, P01)                // term twice
                         + term(qn10, P01) + term(qn01, P01)
                         + term(qr10, P01) + term(qr01, P01);
        const float g01 = msk * sig_arg(fmaf(e01s, -KSL, FOURK));
        const float r01 = __builtin_amdgcn_rcpf(1.0f + q01);
        const float s01 = (d01 >= 0.0f) ? (1.0f - r01) : r01;   // sigm(d01)
        const float e01 = g01 * s01;
        acc[2][q] = e01;
        acc[3][q] = e01;                                        // ref: e01n == e01

        // ---- branch 11 ----
        const float a11  = fabsf(d11);
        const float r11  = __builtin_amdgcn_rcpf(1.0f + q11);
        const float om11 = 1.0f - r11;
        const float ad11 = a11 * om11;
        const float P11  = __builtin_amdgcn_exp2f(-KSL * ad11);
        const float e11s = term(qdn11, P11) + term(q1n1, P11) + term(qnn11, P11)
                         + term(qAn11m, P11) + term(qA1n1m, P11) + term(qA11m, P11);
        const float g11 = msk * sig_arg(fmaf(e11s, -KSL, FOURK));
        const float s11 = (d11 >= 0.0f) ? om11 : r11;
        acc[4][q] = g11 * s11;
        acc[5][q] = fmaf(-s11, g11, g11);

        // ---- branch n11 ---- (hard >0 mask is identity)
        const float Pn11 = __builtin_amdgcn_exp2f(-KSL * fabsf(dn11));
        const float en11s = term(q11, Pn11) + term(q1n1, Pn11) + term(qnn11, Pn11)
                          + term(qA11p, Pn11)
                          + 2.0f * term(qAn11p, Pn11);          // repeated
        const float gn11 = msk * sig_arg(fmaf(en11s, -KSL, FOURK));
        const float rn   = __builtin_amdgcn_rcpf(1.0f + qdn11);
        const float sn11 = (dn11 >= 0.0f) ? (1.0f - rn) : rn;
        acc[6][q] = gn11 * sn11;
        acc[7][q] = fmaf(-sn11, gn11, gn11);
    }

    #pragma unroll
    for (int k = 0; k < 8; ++k) {
        const f2 o = {acc[k][0], acc[k][1]};
        __builtin_nontemporal_store(o, (f2*)(outp + k * PL));
    }
}

extern "C" void kernel_launch(void* const* d_in, const int* in_sizes, int n_in,
                              void* d_out, int out_size, void* d_ws, size_t ws_size,
                              hipStream_t stream) {
    const float* x = (const float*)d_in[0];
    float* out = (float*)d_out;
    dim3 grid(HH, 16 * 3);   // (512 rows, b*3+c); block = one full row of one (b,c)
    dim3 block(256);
    edge_kernel<<<grid, block, 0, stream>>>(x, out);
}

// Round 5
// 446.626 us; speedup vs baseline: 1.0300x; 1.0300x over previous
//
#include <hip/hip_runtime.h>

#define HH 512
#define WW 512
// sigmoid(10*t) = 1/(1 + 2^(-K*t));  K = 10*log2(e)
#define KSL 14.426950408889634f
#define FOURK 57.707801635558536f   // 4*KSL

typedef float f4 __attribute__((ext_vector_type(4)));

// sigmoid(10*t) where arg == -K*t : one v_exp_f32 + one v_rcp_f32
__device__ __forceinline__ float sig_arg(float arg) {
    float e = __builtin_amdgcn_exp2f(arg);
    return __builtin_amdgcn_rcpf(1.0f + e);
}
// Q = 2^(K*|x|)
__device__ __forceinline__ float QE(float x) {
    return __builtin_amdgcn_exp2f(KSL * fabsf(x));
}
// one inner-sum term: sigm(ad - X) = rcp(1 + Q_X * P_ad)
__device__ __forceinline__ float term(float qx, float p) {
    return __builtin_amdgcn_rcpf(fmaf(qx, p, 1.0f));
}

// R2 structure (best measured: 448.1 us) + horizontal-edge exp CSE:
// the row-h edge |x[h,i]-x[h,i+1]| feeds d01 of pixel i+1 and dn01 of pixel i,
// so the 4-px quad needs 5 edge-exps, not 8 (same for the cm-channel row).
__global__ __launch_bounds__(256, 2) void edge_kernel(const float* __restrict__ x,
                                                      float* __restrict__ out) {
    const int tx = threadIdx.x & 63;          // 64 lanes along w, 4 px each
    const int ty = threadIdx.x >> 6;          // 4 rows per block
    const int w0 = blockIdx.x * 256 + tx * 4; // aligned float4 start
    const int h  = blockIdx.y * 4 + ty;
    const int z  = blockIdx.z;                // z = b*3 + c
    const int b  = z / 3;
    const int c  = z - 3 * b;

    float* outp = out + (((size_t)(b * 24 + c * 8) * HH + h) * WW + w0);
    const int PL = HH * WW;                   // plane stride in floats

    if (h < 2 || h >= HH - 2) {               // h-exterior rows: all zero
        const f4 zf = {0.f, 0.f, 0.f, 0.f};
        #pragma unroll
        for (int k = 0; k < 8; ++k)
            __builtin_nontemporal_store(zf, (f4*)(outp + k * PL));
        return;
    }

    const int cm = (c + 2) % 3, cp = (c + 1) % 3;
    const int wl = (w0 == 0) ? 0 : (w0 - 1);
    const int wr = (w0 + 4 >= WW) ? (WW - 1) : (w0 + 4);

    // S = self channel rows h-2..h+1, M = c-1 rows h-2..h, P = c+1 rows h-2..h
    float S[4][6], M[3][6], P[3][6];
    {
        const float* rp = x + (((size_t)(b * 3 + c) * HH + (h - 2)) * WW);
        #pragma unroll
        for (int r = 0; r < 4; ++r) {
            const float* row = rp + r * WW;
            const f4 m = *(const f4*)(row + w0);
            S[r][1] = m.x; S[r][2] = m.y; S[r][3] = m.z; S[r][4] = m.w;
            if (r > 0) { S[r][0] = row[wl]; S[r][5] = row[wr]; }
        }
    }
    {
        const float* rp = x + (((size_t)(b * 3 + cm) * HH + (h - 2)) * WW);
        #pragma unroll
        for (int r = 0; r < 3; ++r) {
            const float* row = rp + r * WW;
            const f4 m = *(const f4*)(row + w0);
            M[r][1] = m.x; M[r][2] = m.y; M[r][3] = m.z; M[r][4] = m.w;
            if (r != 1) { M[r][0] = row[wl]; M[r][5] = row[wr]; }
        }
    }
    {
        const float* rp = x + (((size_t)(b * 3 + cp) * HH + (h - 2)) * WW);
        #pragma unroll
        for (int r = 0; r < 3; ++r) {
            const float* row = rp + r * WW;
            const f4 m = *(const f4*)(row + w0);
            P[r][1] = m.x; P[r][2] = m.y; P[r][3] = m.z; P[r][4] = m.w;
            if (r != 1) { P[r][0] = row[wl]; }   // right halo never used
        }
    }

    // shared horizontal-edge exps: edge i = cols (i, i+1) of the window.
    // dS2[i] signed (sign feeds s01); Q factors from |edge|.
    float dS2[5], qh2[5], qhM2[5];
    #pragma unroll
    for (int i = 0; i < 5; ++i) {
        dS2[i]  = S[2][i] - S[2][i + 1];
        qh2[i]  = QE(dS2[i]);
        qhM2[i] = QE(M[2][i] - M[2][i + 1]);
    }

    float acc[8][4];
    #pragma unroll
    for (int q = 0; q < 4; ++q) {
        const float v = S[2][q + 1], u = S[1][q + 1];
        const float d10   = u           - v;
        const float dn10  = S[3][q + 1] - v;
        const float d01   = dS2[q];            // S[2][q] - S[2][q+1]
        const float d11   = S[1][q]     - v;
        const float dnn11 = S[3][q + 2] - v;
        const float dn11  = S[3][q]     - v;
        const float d1n1  = S[1][q + 2] - v;
        const float r_d10 = S[0][q + 1] - u;
        const float r_d01 = S[1][q]     - u;

        const float rA11m  = M[0][q]     - M[1][q + 1];
        const float rAn11m = M[2][q]     - M[1][q + 1];
        const float rA1n1m = M[0][q + 2] - M[1][q + 1];
        const float rA11p  = P[0][q]     - P[1][q + 1];
        const float rAn11p = P[2][q]     - P[1][q + 1];

        // Q factors: CSE'd horizontal families + per-pixel ones
        const float q01    = qh2[q];           // |d01|
        const float qn01   = qh2[q + 1];       // |dn01|
        const float qA01m  = qhM2[q];
        const float qAn01m = qhM2[q + 1];
        const float q10    = QE(d10),    qn10   = QE(dn10);
        const float q11    = QE(d11),    qdn11  = QE(dn11);
        const float q1n1   = QE(d1n1),   qnn11  = QE(dnn11);
        const float qr10   = QE(r_d10),  qr01   = QE(r_d01);
        const float qA11m  = QE(rA11m),  qAn11m = QE(rAn11m);
        const float qA1n1m = QE(rA1n1m);
        const float qA11p  = QE(rA11p),  qAn11p = QE(rAn11p);

        const float msk = ((w0 + q) >= 2 && (w0 + q) < WW - 2) ? 1.0f : 0.0f;

        // ---- branch 10 ----
        const float a10  = fabsf(d10);
        const float r10  = __builtin_amdgcn_rcpf(1.0f + q10);  // sigm(-a10)
        const float om10 = 1.0f - r10;                          // sigm(a10)
        const float ad10 = a10 * om10;
        const float P10  = __builtin_amdgcn_exp2f(-KSL * ad10);
        const float e10s = term(q01, P10) + term(qn01, P10) + term(qn10, P10)
                         + 2.0f * term(qA01m, P10)             // repeated in ref
                         + term(qAn01m, P10);
        const float g10 = msk * sig_arg(fmaf(e10s, -KSL, FOURK));
        const float s10 = (d10 >= 0.0f) ? om10 : r10;           // sigm(d10)
        acc[0][q] = g10 * s10;
        acc[1][q] = fmaf(-s10, g10, g10);                       // g*(1-s)

        // ---- branch 01 ---- (ref scales ad_01 by sigm(ad_10))
        const float sad10 = __builtin_amdgcn_rcpf(1.0f + P10);  // sigm(ad10)
        const float ad01  = fabsf(d01) * sad10;
        const float P01   = __builtin_amdgcn_exp2f(-KSL * ad01);
        const float e01s = 2.0f * term(q10, P01)                // term twice
                         + term(qn10, P01) + term(qn01, P01)
                         + term(qr10, P01) + term(qr01, P01);
        const float g01 = msk * sig_arg(fmaf(e01s, -KSL, FOURK));
        const float r01 = __builtin_amdgcn_rcpf(1.0f + q01);
        const float s01 = (d01 >= 0.0f) ? (1.0f - r01) : r01;   // sigm(d01)
        const float e01 = g01 * s01;
        acc[2][q] = e01;
        acc[3][q] = e01;                                        // ref: e01n == e01

        // ---- branch 11 ----
        const float a11  = fabsf(d11);
        const float r11  = __builtin_amdgcn_rcpf(1.0f + q11);
        const float om11 = 1.0f - r11;
        const float ad11 = a11 * om11;
        const float P11  = __builtin_amdgcn_exp2f(-KSL * ad11);
        const float e11s = term(qdn11, P11) + term(q1n1, P11) + term(qnn11, P11)
                         + term(qAn11m, P11) + term(qA1n1m, P11) + term(qA11m, P11);
        const float g11 = msk * sig_arg(fmaf(e11s, -KSL, FOURK));
        const float s11 = (d11 >= 0.0f) ? om11 : r11;
        acc[4][q] = g11 * s11;
        acc[5][q] = fmaf(-s11, g11, g11);

        // ---- branch n11 ---- (hard >0 mask is identity)
        const float Pn11 = __builtin_amdgcn_exp2f(-KSL * fabsf(dn11));
        const float en11s = term(q11, Pn11) + term(q1n1, Pn11) + term(qnn11, Pn11)
                          + term(qA11p, Pn11)
                          + 2.0f * term(qAn11p, Pn11);          // repeated
        const float gn11 = msk * sig_arg(fmaf(en11s, -KSL, FOURK));
        const float rn   = __builtin_amdgcn_rcpf(1.0f + qdn11);
        const float sn11 = (dn11 >= 0.0f) ? (1.0f - rn) : rn;
        acc[6][q] = gn11 * sn11;
        acc[7][q] = fmaf(-sn11, gn11, gn11);
    }

    #pragma unroll
    for (int k = 0; k < 8; ++k) {
        const f4 o = {acc[k][0], acc[k][1], acc[k][2], acc[k][3]};
        __builtin_nontemporal_store(o, (f4*)(outp + k * PL));
    }
}

extern "C" void kernel_launch(void* const* d_in, const int* in_sizes, int n_in,
                              void* d_out, int out_size, void* d_ws, size_t ws_size,
                              hipStream_t stream) {
    const float* x = (const float*)d_in[0];
    float* out = (float*)d_out;
    dim3 grid(WW / 256, HH / 4, 16 * 3);  // (2, 128, 48): z = b*3 + c
    dim3 block(256);
    edge_kernel<<<grid, block, 0, stream>>>(x, out);
}